// Round 7
// baseline (250.010 us; speedup 1.0000x reference)
//
#include <hip/hip_runtime.h>

#define NEDGE 625000
#define NNODE 50000
#define EPITCH 68   // uv epilogue pitch in shorts
#define WCPITCH 136 // in-LDS Wcat pitch in shorts: bank stride 4 dwords -> 2-way on b128 (free)

typedef __bf16 bf16x8 __attribute__((ext_vector_type(8)));
typedef unsigned short u16x8 __attribute__((ext_vector_type(8)));
typedef float f32x4 __attribute__((ext_vector_type(4)));

// Native casts: __bf16 cast is RNE in HW; compiler pairs them (v_cvt_pk_bf16_f32).
__device__ __forceinline__ unsigned short f32_bf16(float f) {
  __bf16 h = (__bf16)f;
  return __builtin_bit_cast(unsigned short, h);
}
__device__ __forceinline__ float bf16_f32(unsigned short h) {
  return (float)__builtin_bit_cast(__bf16, h);
}

// ---------------------------------------------------------------------------
// uv: UV[n][0:128] = z[n]@W1_top + b1, UV[n][128:256] = z[n]@W1_bot  (bf16)
// (unchanged from round 6 — invisible in top-5, below ~52 us)
// Each 256-thread block transposes W1 -> Wcat into LDS once, 4 waves x 16
// rows consume B-frags via ds_read_b128. Blocks 0-1 also emit W2T (bf16) and
// idx64_flag for edge_kernel.
// ---------------------------------------------------------------------------
__global__ __launch_bounds__(256, 2) void uv_kernel(
    const float* __restrict__ z, const float* __restrict__ W1,
    const float* __restrict__ b1, const float* __restrict__ W2,
    const int* __restrict__ ei,
    unsigned short* __restrict__ UV, unsigned short* __restrict__ W2T,
    int* __restrict__ idx64_flag)
{
  __shared__ unsigned short lWc[256 * WCPITCH];  // Wcat[j'][k], 69632 B
  __shared__ unsigned short st[4 * 16 * EPITCH]; // per-wave epilogue, 8704 B
  const int t = threadIdx.x, wave = t >> 6, lane = t & 63, c = lane & 15, q = lane >> 4;
  const int bid = blockIdx.x;

  // side jobs for edge_kernel (cross-kernel-boundary handoff)
  if (bid < 2) {
    for (int e = bid * 4096 + t; e < (bid + 1) * 4096; e += 256) {
      int n = e >> 7, k = e & 127;
      W2T[n * 128 + k] = f32_bf16(W2[k * 64 + n]);
    }
  }
  if (bid == 0 && t == 0) {
    int allz = 1;
    for (int j = 1; j < 64; j += 2) allz &= (ei[j] == 0);
    *idx64_flag = allz;
  }

  // in-LDS transpose: lWc[j'][k] = W1[k][j'] (j'<128) | W1[128+k][j'-128]
  for (int e = t; e < 256 * 128; e += 256) {
    int r = e >> 7, j = e & 127;
    float v = W1[r * 128 + j];
    int jp = (r < 128) ? j : (128 + j);
    int k = r & 127;
    lWc[jp * WCPITCH + k] = f32_bf16(v);
  }
  __syncthreads();

  const int mbase = bid * 64 + wave * 16;
  const int rA = mbase + c;
  const int rAc = (rA < NNODE) ? rA : 0;

  // A-fragments: 8 fp32 each at z[row][kt*32+q*8], convert to bf16 in regs
  bf16x8 a0[4];
  {
    const float* zA = z + (size_t)rAc * 128 + q * 8;
    float4 fA[4][2];
#pragma unroll
    for (int kt = 0; kt < 4; ++kt) {
      fA[kt][0] = ((const float4*)(zA + kt * 32))[0];
      fA[kt][1] = ((const float4*)(zA + kt * 32))[1];
    }
#pragma unroll
    for (int kt = 0; kt < 4; ++kt) {
      const float* pa = (const float*)&fA[kt][0];
      bf16x8 oa;
#pragma unroll
      for (int j = 0; j < 8; ++j) oa[j] = (__bf16)pa[j];
      a0[kt] = oa;
    }
  }

  unsigned short* my = &st[wave * 16 * EPITCH];

  for (int nc = 0; nc < 4; ++nc) {
    f32x4 acc[4];
#pragma unroll
    for (int nt = 0; nt < 4; ++nt) {
      f32x4 zz = {0.f, 0.f, 0.f, 0.f};
      acc[nt] = zz;
    }
#pragma unroll
    for (int kt = 0; kt < 4; ++kt)
#pragma unroll
      for (int nt = 0; nt < 4; ++nt) {
        bf16x8 bb = *(const bf16x8*)(&lWc[(nc * 64 + nt * 16 + c) * WCPITCH + kt * 32 + q * 8]);
        acc[nt] = __builtin_amdgcn_mfma_f32_16x16x32_bf16(a0[kt], bb, acc[nt], 0, 0, 0);
      }

    float badd[4];
#pragma unroll
    for (int nt = 0; nt < 4; ++nt) {
      int col = nc * 64 + nt * 16 + c;
      badd[nt] = (col < 128) ? b1[col] : 0.f;
    }

    // stage C-chunk (16 rows x 64 cols = 1024 shorts) in wave-private LDS
#pragma unroll
    for (int nt = 0; nt < 4; ++nt)
#pragma unroll
      for (int reg = 0; reg < 4; ++reg)
        my[(q * 4 + reg) * EPITCH + nt * 16 + c] = f32_bf16(acc[nt][reg] + badd[nt]);
    __asm__ volatile("s_waitcnt lgkmcnt(0)" ::: "memory");  // wave-private: ds_write->ds_read

    // vectorized store: each lane takes 16 shorts (32 B)
    {
      int lrow = lane >> 2, qt = lane & 3;
      int grow = mbase + lrow;
      u16x8 d0 = *(u16x8*)&my[lrow * EPITCH + qt * 16 + 0];
      u16x8 d1 = *(u16x8*)&my[lrow * EPITCH + qt * 16 + 8];
      if (grow < NNODE) {
        u16x8* dst = (u16x8*)(UV + (size_t)grow * 256 + nc * 64 + qt * 16);
        dst[0] = d0;
        dst[1] = d1;
      }
    }
    __asm__ volatile("s_waitcnt lgkmcnt(0)" ::: "memory");  // reads drain before next chunk overwrites
  }
}

// ---------------------------------------------------------------------------
// edge v2: LDS-FREE. W2T (16 KB) fits in the 32 KB per-CU L1 — B-fragments
// read directly from global become L1 hits after the first tile per CU.
// Deletes: 17.4 KB LDS, the staging loop, the only __syncthreads, and the
// 1.875M stride-136 bank conflicts. With zero LDS and VGPR<=64,
// launch_bounds(256,8) demands full 32 waves/CU (was 42% occupancy): the
// gather stream is outstanding-miss-limited, so 2.4x waves => more misses in
// flight. Gather structure itself is PROVEN (51.4-52.6 us, 5x reproduced) —
// unchanged.
// ---------------------------------------------------------------------------
__global__ __launch_bounds__(256, 8) void edge_kernel(
    const int* __restrict__ ei,
    const unsigned short* __restrict__ UV,
    const unsigned short* __restrict__ W2T,
    const float* __restrict__ b2, const float* __restrict__ W3,
    const float* __restrict__ b3, const int* __restrict__ idx64_flag,
    float* __restrict__ out)
{
  const int t = threadIdx.x, wave = t >> 6, lane = t & 63, c = lane & 15, q = lane >> 4;

  const int ebase = blockIdx.x * 128 + wave * 32;
  const int eA = ebase + c, eB = ebase + 16 + c;
  const int eAc = (eA < NEDGE) ? eA : 0;
  const int eBc = (eB < NEDGE) ? eB : 0;
  int sA, dA, sB, dB;
  if (*idx64_flag) {
    const long long* e64 = (const long long*)ei;
    sA = (int)e64[eAc]; dA = (int)e64[NEDGE + eAc];
    sB = (int)e64[eBc]; dB = (int)e64[NEDGE + eBc];
  } else {
    sA = ei[eAc]; dA = ei[NEDGE + eAc];
    sB = ei[eBc]; dB = ei[NEDGE + eBc];
  }

  // 16 independent 16B gather loads (4 per kt): U-half of src, V-half of dst
  const u16x8* pAu = (const u16x8*)(UV + (size_t)sA * 256) + q;
  const u16x8* pAv = (const u16x8*)(UV + (size_t)dA * 256 + 128) + q;
  const u16x8* pBu = (const u16x8*)(UV + (size_t)sB * 256) + q;
  const u16x8* pBv = (const u16x8*)(UV + (size_t)dB * 256 + 128) + q;
  u16x8 rAu[4], rAv[4], rBu[4], rBv[4];
#pragma unroll
  for (int kt = 0; kt < 4; ++kt) {
    rAu[kt] = pAu[kt * 4];
    rAv[kt] = pAv[kt * 4];
    rBu[kt] = pBu[kt * 4];
    rBv[kt] = pBv[kt * 4];
  }

  f32x4 acc[2][4];
#pragma unroll
  for (int mt = 0; mt < 2; ++mt)
#pragma unroll
    for (int nt = 0; nt < 4; ++nt) {
      f32x4 zz = {0.f, 0.f, 0.f, 0.f};
      acc[mt][nt] = zz;
    }

#pragma unroll
  for (int kt = 0; kt < 4; ++kt) {
    bf16x8 a0, a1;
#pragma unroll
    for (int j = 0; j < 8; ++j) {
      a0[j] = (__bf16)fmaxf(bf16_f32(rAu[kt][j]) + bf16_f32(rAv[kt][j]), 0.f);
      a1[j] = (__bf16)fmaxf(bf16_f32(rBu[kt][j]) + bf16_f32(rBv[kt][j]), 0.f);
    }
#pragma unroll
    for (int nt = 0; nt < 4; ++nt) {
      // direct global read; W2T is L1-resident (16 KB < 32 KB L1)
      bf16x8 bb = *(const bf16x8*)(W2T + (nt * 16 + c) * 128 + kt * 32 + q * 8);
      acc[0][nt] = __builtin_amdgcn_mfma_f32_16x16x32_bf16(a0, bb, acc[0][nt], 0, 0, 0);
      acc[1][nt] = __builtin_amdgcn_mfma_f32_16x16x32_bf16(a1, bb, acc[1][nt], 0, 0, 0);
    }
  }

  // layer-2 bias+relu and layer-3 dot in fp32; reduce over the 16 c-lanes
  float b2v[4], w3v[4];
#pragma unroll
  for (int nt = 0; nt < 4; ++nt) {
    int n = nt * 16 + c;
    b2v[nt] = b2[n];
    w3v[nt] = W3[n];
  }
  float bias3 = b3[0];

#pragma unroll
  for (int mt = 0; mt < 2; ++mt) {
    float p0 = 0.f, p1 = 0.f, p2 = 0.f, p3 = 0.f;
#pragma unroll
    for (int nt = 0; nt < 4; ++nt) {
      p0 += fmaxf(acc[mt][nt][0] + b2v[nt], 0.f) * w3v[nt];
      p1 += fmaxf(acc[mt][nt][1] + b2v[nt], 0.f) * w3v[nt];
      p2 += fmaxf(acc[mt][nt][2] + b2v[nt], 0.f) * w3v[nt];
      p3 += fmaxf(acc[mt][nt][3] + b2v[nt], 0.f) * w3v[nt];
    }
#pragma unroll
    for (int m = 1; m < 16; m <<= 1) {
      p0 += __shfl_xor(p0, m, 64);
      p1 += __shfl_xor(p1, m, 64);
      p2 += __shfl_xor(p2, m, 64);
      p3 += __shfl_xor(p3, m, 64);
    }
    if (c == 0) {
      int eb = ebase + mt * 16 + q * 4;
      if (eb + 0 < NEDGE) out[eb + 0] = p0 + bias3;
      if (eb + 1 < NEDGE) out[eb + 1] = p1 + bias3;
      if (eb + 2 < NEDGE) out[eb + 2] = p2 + bias3;
      if (eb + 3 < NEDGE) out[eb + 3] = p3 + bias3;
    }
  }
}

extern "C" void kernel_launch(void* const* d_in, const int* in_sizes, int n_in,
                              void* d_out, int out_size, void* d_ws, size_t ws_size,
                              hipStream_t stream) {
  const float* z  = (const float*)d_in[0];
  const int*   ei = (const int*)d_in[1];
  const float* W1 = (const float*)d_in[2];
  const float* b1 = (const float*)d_in[3];
  const float* W2 = (const float*)d_in[4];
  const float* b2 = (const float*)d_in[5];
  const float* W3 = (const float*)d_in[6];
  const float* b3 = (const float*)d_in[7];
  float* out = (float*)d_out;

  unsigned short* UV  = (unsigned short*)d_ws;       // 50000*256 bf16 = 25.6 MB
  unsigned short* W2T = UV + (size_t)NNODE * 256;    // 64*128 bf16
  int* idx64_flag     = (int*)(W2T + 64 * 128);

  uv_kernel<<<dim3((NNODE + 63) / 64), dim3(256), 0, stream>>>(
      z, W1, b1, W2, ei, UV, W2T, idx64_flag);
  edge_kernel<<<dim3((NEDGE + 127) / 128), dim3(256), 0, stream>>>(
      ei, UV, W2T, b2, W3, b3, idx64_flag, out);
}

// Round 8
// 210.602 us; speedup vs baseline: 1.1871x; 1.1871x over previous
//
#include <hip/hip_runtime.h>

#define NEDGE 625000
#define NNODE 50000
#define WPITCH 136  // lW pitch in shorts: 272 B rows -> 2-way bank aliasing on b128 (free)
#define EPITCH 68   // uv epilogue pitch in shorts
#define WCPITCH 136 // in-LDS Wcat pitch in shorts

#define NBUCK 391   // src>>7 buckets (50000/128)
#define BCAP 2048   // per-bucket capacity: lambda=1600, sigma=40 -> 11 sigma
#define OVCAP 4096  // overflow side-list
#define BSTRIDE 16  // bins padded to one per 64B line (atomic spread)

typedef __bf16 bf16x8 __attribute__((ext_vector_type(8)));
typedef unsigned short u16x8 __attribute__((ext_vector_type(8)));
typedef float f32x4 __attribute__((ext_vector_type(4)));

__device__ __forceinline__ unsigned short f32_bf16(float f) {
  __bf16 h = (__bf16)f;
  return __builtin_bit_cast(unsigned short, h);
}
__device__ __forceinline__ float bf16_f32(unsigned short h) {
  return (float)__builtin_bit_cast(__bf16, h);
}

// ---------------------------------------------------------------------------
// uv: UV[n][0:128] = z[n]@W1_top + b1, UV[n][128:256] = z[n]@W1_bot  (bf16)
// (r6-proven; invisible in top-5). Side jobs: W2T, idx64_flag, and zeroing
// the sort bins (bins may be null when sorted path disabled).
// ---------------------------------------------------------------------------
__global__ __launch_bounds__(256, 2) void uv_kernel(
    const float* __restrict__ z, const float* __restrict__ W1,
    const float* __restrict__ b1, const float* __restrict__ W2,
    const int* __restrict__ ei,
    unsigned short* __restrict__ UV, unsigned short* __restrict__ W2T,
    int* __restrict__ idx64_flag, int* __restrict__ bins)
{
  __shared__ unsigned short lWc[256 * WCPITCH];  // Wcat[j'][k], 69632 B
  __shared__ unsigned short st[4 * 16 * EPITCH]; // per-wave epilogue, 8704 B
  const int t = threadIdx.x, wave = t >> 6, lane = t & 63, c = lane & 15, q = lane >> 4;
  const int bid = blockIdx.x;

  // side jobs for the later kernels (cross-kernel-boundary handoff)
  if (bid < 2) {
    for (int e = bid * 4096 + t; e < (bid + 1) * 4096; e += 256) {
      int n = e >> 7, k = e & 127;
      W2T[n * 128 + k] = f32_bf16(W2[k * 64 + n]);
    }
  }
  if (bid == 0 && t == 0) {
    int allz = 1;
    for (int j = 1; j < 64; j += 2) allz &= (ei[j] == 0);
    *idx64_flag = allz;
  }
  if (bid == 2 && bins != nullptr) {
    for (int i = t; i < NBUCK * BSTRIDE + BSTRIDE; i += 256) bins[i] = 0;
  }

  // in-LDS transpose: lWc[j'][k] = W1[k][j'] (j'<128) | W1[128+k][j'-128]
  for (int e = t; e < 256 * 128; e += 256) {
    int r = e >> 7, j = e & 127;
    float v = W1[r * 128 + j];
    int jp = (r < 128) ? j : (128 + j);
    int k = r & 127;
    lWc[jp * WCPITCH + k] = f32_bf16(v);
  }
  __syncthreads();

  const int mbase = bid * 64 + wave * 16;
  const int rA = mbase + c;
  const int rAc = (rA < NNODE) ? rA : 0;

  bf16x8 a0[4];
  {
    const float* zA = z + (size_t)rAc * 128 + q * 8;
    float4 fA[4][2];
#pragma unroll
    for (int kt = 0; kt < 4; ++kt) {
      fA[kt][0] = ((const float4*)(zA + kt * 32))[0];
      fA[kt][1] = ((const float4*)(zA + kt * 32))[1];
    }
#pragma unroll
    for (int kt = 0; kt < 4; ++kt) {
      const float* pa = (const float*)&fA[kt][0];
      bf16x8 oa;
#pragma unroll
      for (int j = 0; j < 8; ++j) oa[j] = (__bf16)pa[j];
      a0[kt] = oa;
    }
  }

  unsigned short* my = &st[wave * 16 * EPITCH];

  for (int nc = 0; nc < 4; ++nc) {
    f32x4 acc[4];
#pragma unroll
    for (int nt = 0; nt < 4; ++nt) {
      f32x4 zz = {0.f, 0.f, 0.f, 0.f};
      acc[nt] = zz;
    }
#pragma unroll
    for (int kt = 0; kt < 4; ++kt)
#pragma unroll
      for (int nt = 0; nt < 4; ++nt) {
        bf16x8 bb = *(const bf16x8*)(&lWc[(nc * 64 + nt * 16 + c) * WCPITCH + kt * 32 + q * 8]);
        acc[nt] = __builtin_amdgcn_mfma_f32_16x16x32_bf16(a0[kt], bb, acc[nt], 0, 0, 0);
      }

    float badd[4];
#pragma unroll
    for (int nt = 0; nt < 4; ++nt) {
      int col = nc * 64 + nt * 16 + c;
      badd[nt] = (col < 128) ? b1[col] : 0.f;
    }

#pragma unroll
    for (int nt = 0; nt < 4; ++nt)
#pragma unroll
      for (int reg = 0; reg < 4; ++reg)
        my[(q * 4 + reg) * EPITCH + nt * 16 + c] = f32_bf16(acc[nt][reg] + badd[nt]);
    __asm__ volatile("s_waitcnt lgkmcnt(0)" ::: "memory");

    {
      int lrow = lane >> 2, qt = lane & 3;
      int grow = mbase + lrow;
      u16x8 d0 = *(u16x8*)&my[lrow * EPITCH + qt * 16 + 0];
      u16x8 d1 = *(u16x8*)&my[lrow * EPITCH + qt * 16 + 8];
      if (grow < NNODE) {
        u16x8* dst = (u16x8*)(UV + (size_t)grow * 256 + nc * 64 + qt * 16);
        dst[0] = d0;
        dst[1] = d1;
      }
    }
    __asm__ volatile("s_waitcnt lgkmcnt(0)" ::: "memory");
  }
}

// ---------------------------------------------------------------------------
// sort: bucket edges by src>>7 (scan-free: fixed BCAP slots per bucket +
// overflow side-list). Emits int32 sSrc/sDst/sId regardless of input width.
// Bins padded to 1/64B-line so same-bucket atomics don't share lines.
// ---------------------------------------------------------------------------
__global__ __launch_bounds__(256) void sort_kernel(
    const int* __restrict__ ei, int* __restrict__ bins,
    int* __restrict__ sSrc, int* __restrict__ sDst, int* __restrict__ sId)
{
  __shared__ int sflag;
  const int t = threadIdx.x;
  if (t < 64) {
    int v = ei[t];
    unsigned long long odd_nz = __ballot((t & 1) && v != 0);
    if (t == 0) sflag = (odd_nz == 0ull) ? 1 : 0;
  }
  __syncthreads();
  int e = blockIdx.x * 256 + t;
  if (e >= NEDGE) return;
  int src, dst;
  if (sflag) {
    const long long* e64 = (const long long*)ei;
    src = (int)e64[e];
    dst = (int)e64[NEDGE + e];
  } else {
    src = ei[e];
    dst = ei[NEDGE + e];
  }
  int b = src >> 7;
  int pos = atomicAdd(&bins[b * BSTRIDE], 1);
  int slot;
  if (pos < BCAP) {
    slot = b * BCAP + pos;
  } else {
    int op = atomicAdd(&bins[NBUCK * BSTRIDE], 1);
    if (op >= OVCAP) return;  // unreachable for this distribution (11-sigma cap)
    slot = NBUCK * BCAP + op;
  }
  sSrc[slot] = src;
  sDst[slot] = dst;
  sId[slot] = e;
}

// ---------------------------------------------------------------------------
// edge (sorted): gather/MFMA core BYTE-IDENTICAL to the 6x-reproduced 52us
// structure (LDS W2T staging, (256,4), no sched fences). Only the edge-index
// source changes: coalesced reads of bucketed sSrc/sDst; out scattered via
// sId. Tiles within a bucket share a 128-row U-range (32 KB) -> U-half
// gathers become L2-hits; random misses ~halve.
// ---------------------------------------------------------------------------
__global__ __launch_bounds__(256, 4) void edge_kernel_sorted(
    const int* __restrict__ bins,
    const int* __restrict__ sSrc, const int* __restrict__ sDst,
    const int* __restrict__ sId,
    const unsigned short* __restrict__ UV,
    const unsigned short* __restrict__ W2T,
    const float* __restrict__ b2, const float* __restrict__ W3,
    const float* __restrict__ b3, float* __restrict__ out)
{
  __shared__ unsigned short lW[64 * WPITCH];
  const int t = threadIdx.x, wave = t >> 6, lane = t & 63, c = lane & 15, q = lane >> 4;

  {  // stage W2T once (16 KB shared by all waves) — before any exit
    int n = t >> 2, qd = t & 3;
    const u16x8* src = (const u16x8*)(W2T + n * 128 + qd * 32);
    u16x8* dst = (u16x8*)(&lW[n * WPITCH + qd * 32]);
#pragma unroll
    for (int i = 0; i < 4; ++i) dst[i] = src[i];
  }
  __syncthreads();  // the only barrier

  const int b = blockIdx.x;
  int base, navail;
  if (b < NBUCK * (BCAP / 128)) {
    int bucket = b >> 4, tile = b & 15;
    int cnt = bins[bucket * BSTRIDE];
    if (cnt > BCAP) cnt = BCAP;
    navail = cnt - tile * 128;
    base = bucket * BCAP + tile * 128;
  } else {
    int tile = b - NBUCK * (BCAP / 128);
    int cnt = bins[NBUCK * BSTRIDE];
    if (cnt > OVCAP) cnt = OVCAP;
    navail = cnt - tile * 128;
    base = NBUCK * BCAP + tile * 128;
  }
  if (navail <= 0) return;           // block-uniform
  if (navail > 128) navail = 128;
  if (wave * 32 >= navail) return;   // wave-uniform; no barriers follow

  const int liA = wave * 32 + c, liB = wave * 32 + 16 + c;
  const int liAc = (liA < navail) ? liA : 0;
  const int liBc = (liB < navail) ? liB : 0;
  const int sA = sSrc[base + liAc], dA = sDst[base + liAc];
  const int sB = sSrc[base + liBc], dB = sDst[base + liBc];

  // 16 independent 16B gather loads (4 per kt): U-half of src, V-half of dst
  const u16x8* pAu = (const u16x8*)(UV + (size_t)sA * 256) + q;
  const u16x8* pAv = (const u16x8*)(UV + (size_t)dA * 256 + 128) + q;
  const u16x8* pBu = (const u16x8*)(UV + (size_t)sB * 256) + q;
  const u16x8* pBv = (const u16x8*)(UV + (size_t)dB * 256 + 128) + q;
  u16x8 rAu[4], rAv[4], rBu[4], rBv[4];
#pragma unroll
  for (int kt = 0; kt < 4; ++kt) {
    rAu[kt] = pAu[kt * 4];
    rAv[kt] = pAv[kt * 4];
    rBu[kt] = pBu[kt * 4];
    rBv[kt] = pBv[kt * 4];
  }

  f32x4 acc[2][4];
#pragma unroll
  for (int mt = 0; mt < 2; ++mt)
#pragma unroll
    for (int nt = 0; nt < 4; ++nt) {
      f32x4 zz = {0.f, 0.f, 0.f, 0.f};
      acc[mt][nt] = zz;
    }

#pragma unroll
  for (int kt = 0; kt < 4; ++kt) {
    bf16x8 a0, a1;
#pragma unroll
    for (int j = 0; j < 8; ++j) {
      a0[j] = (__bf16)fmaxf(bf16_f32(rAu[kt][j]) + bf16_f32(rAv[kt][j]), 0.f);
      a1[j] = (__bf16)fmaxf(bf16_f32(rBu[kt][j]) + bf16_f32(rBv[kt][j]), 0.f);
    }
#pragma unroll
    for (int nt = 0; nt < 4; ++nt) {
      bf16x8 bb = *(const bf16x8*)(&lW[(nt * 16 + c) * WPITCH + kt * 32 + q * 8]);
      acc[0][nt] = __builtin_amdgcn_mfma_f32_16x16x32_bf16(a0, bb, acc[0][nt], 0, 0, 0);
      acc[1][nt] = __builtin_amdgcn_mfma_f32_16x16x32_bf16(a1, bb, acc[1][nt], 0, 0, 0);
    }
  }

  float b2v[4], w3v[4];
#pragma unroll
  for (int nt = 0; nt < 4; ++nt) {
    int n = nt * 16 + c;
    b2v[nt] = b2[n];
    w3v[nt] = W3[n];
  }
  float bias3 = b3[0];

#pragma unroll
  for (int mt = 0; mt < 2; ++mt) {
    float p0 = 0.f, p1 = 0.f, p2 = 0.f, p3 = 0.f;
#pragma unroll
    for (int nt = 0; nt < 4; ++nt) {
      p0 += fmaxf(acc[mt][nt][0] + b2v[nt], 0.f) * w3v[nt];
      p1 += fmaxf(acc[mt][nt][1] + b2v[nt], 0.f) * w3v[nt];
      p2 += fmaxf(acc[mt][nt][2] + b2v[nt], 0.f) * w3v[nt];
      p3 += fmaxf(acc[mt][nt][3] + b2v[nt], 0.f) * w3v[nt];
    }
#pragma unroll
    for (int m = 1; m < 16; m <<= 1) {
      p0 += __shfl_xor(p0, m, 64);
      p1 += __shfl_xor(p1, m, 64);
      p2 += __shfl_xor(p2, m, 64);
      p3 += __shfl_xor(p3, m, 64);
    }
    if (c == 0) {
      int lb = wave * 32 + mt * 16 + q * 4;
      if (lb + 0 < navail) out[sId[base + lb + 0]] = p0 + bias3;
      if (lb + 1 < navail) out[sId[base + lb + 1]] = p1 + bias3;
      if (lb + 2 < navail) out[sId[base + lb + 2]] = p2 + bias3;
      if (lb + 3 < navail) out[sId[base + lb + 3]] = p3 + bias3;
    }
  }
}

// ---------------------------------------------------------------------------
// edge (unsorted fallback) — byte-identical to the r6-proven 52us kernel.
// Used only when ws_size can't hold the sort buffers.
// ---------------------------------------------------------------------------
__global__ __launch_bounds__(256, 4) void edge_kernel(
    const int* __restrict__ ei,
    const unsigned short* __restrict__ UV,
    const unsigned short* __restrict__ W2T,
    const float* __restrict__ b2, const float* __restrict__ W3,
    const float* __restrict__ b3, const int* __restrict__ idx64_flag,
    float* __restrict__ out)
{
  __shared__ unsigned short lW[64 * WPITCH];
  const int t = threadIdx.x, wave = t >> 6, lane = t & 63, c = lane & 15, q = lane >> 4;

  {
    int n = t >> 2, qd = t & 3;
    const u16x8* src = (const u16x8*)(W2T + n * 128 + qd * 32);
    u16x8* dst = (u16x8*)(&lW[n * WPITCH + qd * 32]);
#pragma unroll
    for (int i = 0; i < 4; ++i) dst[i] = src[i];
  }
  __syncthreads();

  const int ebase = blockIdx.x * 128 + wave * 32;
  const int eA = ebase + c, eB = ebase + 16 + c;
  const int eAc = (eA < NEDGE) ? eA : 0;
  const int eBc = (eB < NEDGE) ? eB : 0;
  int sA, dA, sB, dB;
  if (*idx64_flag) {
    const long long* e64 = (const long long*)ei;
    sA = (int)e64[eAc]; dA = (int)e64[NEDGE + eAc];
    sB = (int)e64[eBc]; dB = (int)e64[NEDGE + eBc];
  } else {
    sA = ei[eAc]; dA = ei[NEDGE + eAc];
    sB = ei[eBc]; dB = ei[NEDGE + eBc];
  }

  const u16x8* pAu = (const u16x8*)(UV + (size_t)sA * 256) + q;
  const u16x8* pAv = (const u16x8*)(UV + (size_t)dA * 256 + 128) + q;
  const u16x8* pBu = (const u16x8*)(UV + (size_t)sB * 256) + q;
  const u16x8* pBv = (const u16x8*)(UV + (size_t)dB * 256 + 128) + q;
  u16x8 rAu[4], rAv[4], rBu[4], rBv[4];
#pragma unroll
  for (int kt = 0; kt < 4; ++kt) {
    rAu[kt] = pAu[kt * 4];
    rAv[kt] = pAv[kt * 4];
    rBu[kt] = pBu[kt * 4];
    rBv[kt] = pBv[kt * 4];
  }

  f32x4 acc[2][4];
#pragma unroll
  for (int mt = 0; mt < 2; ++mt)
#pragma unroll
    for (int nt = 0; nt < 4; ++nt) {
      f32x4 zz = {0.f, 0.f, 0.f, 0.f};
      acc[mt][nt] = zz;
    }

#pragma unroll
  for (int kt = 0; kt < 4; ++kt) {
    bf16x8 a0, a1;
#pragma unroll
    for (int j = 0; j < 8; ++j) {
      a0[j] = (__bf16)fmaxf(bf16_f32(rAu[kt][j]) + bf16_f32(rAv[kt][j]), 0.f);
      a1[j] = (__bf16)fmaxf(bf16_f32(rBu[kt][j]) + bf16_f32(rBv[kt][j]), 0.f);
    }
#pragma unroll
    for (int nt = 0; nt < 4; ++nt) {
      bf16x8 bb = *(const bf16x8*)(&lW[(nt * 16 + c) * WPITCH + kt * 32 + q * 8]);
      acc[0][nt] = __builtin_amdgcn_mfma_f32_16x16x32_bf16(a0, bb, acc[0][nt], 0, 0, 0);
      acc[1][nt] = __builtin_amdgcn_mfma_f32_16x16x32_bf16(a1, bb, acc[1][nt], 0, 0, 0);
    }
  }

  float b2v[4], w3v[4];
#pragma unroll
  for (int nt = 0; nt < 4; ++nt) {
    int n = nt * 16 + c;
    b2v[nt] = b2[n];
    w3v[nt] = W3[n];
  }
  float bias3 = b3[0];

#pragma unroll
  for (int mt = 0; mt < 2; ++mt) {
    float p0 = 0.f, p1 = 0.f, p2 = 0.f, p3 = 0.f;
#pragma unroll
    for (int nt = 0; nt < 4; ++nt) {
      p0 += fmaxf(acc[mt][nt][0] + b2v[nt], 0.f) * w3v[nt];
      p1 += fmaxf(acc[mt][nt][1] + b2v[nt], 0.f) * w3v[nt];
      p2 += fmaxf(acc[mt][nt][2] + b2v[nt], 0.f) * w3v[nt];
      p3 += fmaxf(acc[mt][nt][3] + b2v[nt], 0.f) * w3v[nt];
    }
#pragma unroll
    for (int m = 1; m < 16; m <<= 1) {
      p0 += __shfl_xor(p0, m, 64);
      p1 += __shfl_xor(p1, m, 64);
      p2 += __shfl_xor(p2, m, 64);
      p3 += __shfl_xor(p3, m, 64);
    }
    if (c == 0) {
      int eb = ebase + mt * 16 + q * 4;
      if (eb + 0 < NEDGE) out[eb + 0] = p0 + bias3;
      if (eb + 1 < NEDGE) out[eb + 1] = p1 + bias3;
      if (eb + 2 < NEDGE) out[eb + 2] = p2 + bias3;
      if (eb + 3 < NEDGE) out[eb + 3] = p3 + bias3;
    }
  }
}

extern "C" void kernel_launch(void* const* d_in, const int* in_sizes, int n_in,
                              void* d_out, int out_size, void* d_ws, size_t ws_size,
                              hipStream_t stream) {
  const float* z  = (const float*)d_in[0];
  const int*   ei = (const int*)d_in[1];
  const float* W1 = (const float*)d_in[2];
  const float* b1 = (const float*)d_in[3];
  const float* W2 = (const float*)d_in[4];
  const float* b2 = (const float*)d_in[5];
  const float* W3 = (const float*)d_in[6];
  const float* b3 = (const float*)d_in[7];
  float* out = (float*)d_out;

  char* ws = (char*)d_ws;
  size_t off = 0;
  unsigned short* UV = (unsigned short*)(ws + off); off += (size_t)NNODE * 256 * 2;
  unsigned short* W2T = (unsigned short*)(ws + off); off += 64 * 128 * 2;
  int* idx64_flag = (int*)(ws + off); off += 16;
  int* bins = (int*)(ws + off); off += (size_t)(NBUCK * BSTRIDE + BSTRIDE) * 4;
  const size_t nslot = (size_t)NBUCK * BCAP + OVCAP;
  int* sSrc = (int*)(ws + off); off += nslot * 4;
  int* sDst = (int*)(ws + off); off += nslot * 4;
  int* sId  = (int*)(ws + off); off += nslot * 4;
  const bool do_sort = (ws_size >= off);

  uv_kernel<<<dim3((NNODE + 63) / 64), dim3(256), 0, stream>>>(
      z, W1, b1, W2, ei, UV, W2T, idx64_flag, do_sort ? bins : nullptr);
  if (do_sort) {
    sort_kernel<<<dim3((NEDGE + 255) / 256), dim3(256), 0, stream>>>(
        ei, bins, sSrc, sDst, sId);
    edge_kernel_sorted<<<dim3(NBUCK * (BCAP / 128) + OVCAP / 128), dim3(256), 0, stream>>>(
        bins, sSrc, sDst, sId, UV, W2T, b2, W3, b3, out);
  } else {
    edge_kernel<<<dim3((NEDGE + 127) / 128), dim3(256), 0, stream>>>(
        ei, UV, W2T, b2, W3, b3, idx64_flag, out);
  }
}

// Round 9
// 152.619 us; speedup vs baseline: 1.6381x; 1.3799x over previous
//
#include <hip/hip_runtime.h>

#define NEDGE 625000
#define NNODE 50000
#define WPITCH 136  // lW pitch in shorts: 272 B rows -> 2-way bank aliasing on b128 (free)
#define EPITCH 68   // uv epilogue pitch in shorts
#define WCPITCH 136 // in-LDS Wcat pitch in shorts: bank stride 4 dwords -> 2-way on b128 (free)

typedef __bf16 bf16x8 __attribute__((ext_vector_type(8)));
typedef unsigned short u16x8 __attribute__((ext_vector_type(8)));
typedef float f32x4 __attribute__((ext_vector_type(4)));

// Native casts: __bf16 cast is RNE in HW; compiler pairs them (v_cvt_pk_bf16_f32).
__device__ __forceinline__ unsigned short f32_bf16(float f) {
  __bf16 h = (__bf16)f;
  return __builtin_bit_cast(unsigned short, h);
}
__device__ __forceinline__ float bf16_f32(unsigned short h) {
  return (float)__builtin_bit_cast(__bf16, h);
}

// ---------------------------------------------------------------------------
// uv: UV[n][0:128] = z[n]@W1_top + b1, UV[n][128:256] = z[n]@W1_bot  (bf16)
// Round-6 proven config (best total 152.3 us). Each 256-thread block
// transposes W1 -> Wcat into LDS once (69.6 KB, pitch 136), then 4 waves x
// 16 rows consume B-frags via ds_read_b128 (2-way aliasing = free).
// Blocks 0-1 also emit W2T (bf16) and idx64_flag for edge_kernel.
// ---------------------------------------------------------------------------
__global__ __launch_bounds__(256, 2) void uv_kernel(
    const float* __restrict__ z, const float* __restrict__ W1,
    const float* __restrict__ b1, const float* __restrict__ W2,
    const int* __restrict__ ei,
    unsigned short* __restrict__ UV, unsigned short* __restrict__ W2T,
    int* __restrict__ idx64_flag)
{
  __shared__ unsigned short lWc[256 * WCPITCH];  // Wcat[j'][k], 69632 B
  __shared__ unsigned short st[4 * 16 * EPITCH]; // per-wave epilogue, 8704 B
  const int t = threadIdx.x, wave = t >> 6, lane = t & 63, c = lane & 15, q = lane >> 4;
  const int bid = blockIdx.x;

  // side jobs for edge_kernel (cross-kernel-boundary handoff)
  if (bid < 2) {
    for (int e = bid * 4096 + t; e < (bid + 1) * 4096; e += 256) {
      int n = e >> 7, k = e & 127;
      W2T[n * 128 + k] = f32_bf16(W2[k * 64 + n]);
    }
  }
  if (bid == 0 && t == 0) {
    int allz = 1;
    for (int j = 1; j < 64; j += 2) allz &= (ei[j] == 0);
    *idx64_flag = allz;
  }

  // in-LDS transpose: lWc[j'][k] = W1[k][j'] (j'<128) | W1[128+k][j'-128]
  for (int e = t; e < 256 * 128; e += 256) {
    int r = e >> 7, j = e & 127;
    float v = W1[r * 128 + j];
    int jp = (r < 128) ? j : (128 + j);
    int k = r & 127;
    lWc[jp * WCPITCH + k] = f32_bf16(v);
  }
  __syncthreads();

  const int mbase = bid * 64 + wave * 16;
  const int rA = mbase + c;
  const int rAc = (rA < NNODE) ? rA : 0;

  // A-fragments: 8 fp32 each at z[row][kt*32+q*8], convert to bf16 in regs
  bf16x8 a0[4];
  {
    const float* zA = z + (size_t)rAc * 128 + q * 8;
    float4 fA[4][2];
#pragma unroll
    for (int kt = 0; kt < 4; ++kt) {
      fA[kt][0] = ((const float4*)(zA + kt * 32))[0];
      fA[kt][1] = ((const float4*)(zA + kt * 32))[1];
    }
#pragma unroll
    for (int kt = 0; kt < 4; ++kt) {
      const float* pa = (const float*)&fA[kt][0];
      bf16x8 oa;
#pragma unroll
      for (int j = 0; j < 8; ++j) oa[j] = (__bf16)pa[j];
      a0[kt] = oa;
    }
  }

  unsigned short* my = &st[wave * 16 * EPITCH];

  for (int nc = 0; nc < 4; ++nc) {
    f32x4 acc[4];
#pragma unroll
    for (int nt = 0; nt < 4; ++nt) {
      f32x4 zz = {0.f, 0.f, 0.f, 0.f};
      acc[nt] = zz;
    }
#pragma unroll
    for (int kt = 0; kt < 4; ++kt)
#pragma unroll
      for (int nt = 0; nt < 4; ++nt) {
        bf16x8 bb = *(const bf16x8*)(&lWc[(nc * 64 + nt * 16 + c) * WCPITCH + kt * 32 + q * 8]);
        acc[nt] = __builtin_amdgcn_mfma_f32_16x16x32_bf16(a0[kt], bb, acc[nt], 0, 0, 0);
      }

    float badd[4];
#pragma unroll
    for (int nt = 0; nt < 4; ++nt) {
      int col = nc * 64 + nt * 16 + c;
      badd[nt] = (col < 128) ? b1[col] : 0.f;
    }

    // stage C-chunk (16 rows x 64 cols = 1024 shorts) in wave-private LDS
#pragma unroll
    for (int nt = 0; nt < 4; ++nt)
#pragma unroll
      for (int reg = 0; reg < 4; ++reg)
        my[(q * 4 + reg) * EPITCH + nt * 16 + c] = f32_bf16(acc[nt][reg] + badd[nt]);
    __asm__ volatile("s_waitcnt lgkmcnt(0)" ::: "memory");  // wave-private: ds_write->ds_read

    // vectorized store: each lane takes 16 shorts (32 B)
    {
      int lrow = lane >> 2, qt = lane & 3;
      int grow = mbase + lrow;
      u16x8 d0 = *(u16x8*)&my[lrow * EPITCH + qt * 16 + 0];
      u16x8 d1 = *(u16x8*)&my[lrow * EPITCH + qt * 16 + 8];
      if (grow < NNODE) {
        u16x8* dst = (u16x8*)(UV + (size_t)grow * 256 + nc * 64 + qt * 16);
        dst[0] = d0;
        dst[1] = d1;
      }
    }
    __asm__ volatile("s_waitcnt lgkmcnt(0)" ::: "memory");  // reads drain before next chunk overwrites
  }
}

// ---------------------------------------------------------------------------
// edge: gather MFMA A-frags DIRECTLY from UV (no h1 LDS, no gather barrier):
// lane (c,q) reads 16B granules of rows src/dst; add+relu in regs -> frags.
// h2 = relu(h1@W2+b2) via MFMA (W2T staged once in LDS); score fp32 epilogue.
// PROVEN config (51.4-52.6 us, 6x reproduced): native casts +
// launch_bounds(256,4), NO sched fence. Bidirectional sweep complete:
// deeper queues (r2) worse, more waves (r7: spills) worse, less HBM traffic
// via src-bucketing (r8: FETCH 135->108 MB) ALSO worse — the kernel sits at
// the random-64B-segment service equilibrium (~320 MB mandatory gathers at
// ~6.1 TB/s blended L1/L2/L3 ~= 52 us). DO NOT TOUCH.
// ---------------------------------------------------------------------------
__global__ __launch_bounds__(256, 4) void edge_kernel(
    const int* __restrict__ ei,
    const unsigned short* __restrict__ UV,
    const unsigned short* __restrict__ W2T,
    const float* __restrict__ b2, const float* __restrict__ W3,
    const float* __restrict__ b3, const int* __restrict__ idx64_flag,
    float* __restrict__ out)
{
  __shared__ unsigned short lW[64 * WPITCH];
  const int t = threadIdx.x, wave = t >> 6, lane = t & 63, c = lane & 15, q = lane >> 4;

  {  // stage W2T once (16 KB shared by all waves)
    int n = t >> 2, qd = t & 3;
    const u16x8* src = (const u16x8*)(W2T + n * 128 + qd * 32);
    u16x8* dst = (u16x8*)(&lW[n * WPITCH + qd * 32]);
#pragma unroll
    for (int i = 0; i < 4; ++i) dst[i] = src[i];
  }
  __syncthreads();  // the only barrier in this kernel

  const int ebase = blockIdx.x * 128 + wave * 32;
  const int eA = ebase + c, eB = ebase + 16 + c;
  const int eAc = (eA < NEDGE) ? eA : 0;
  const int eBc = (eB < NEDGE) ? eB : 0;
  int sA, dA, sB, dB;
  if (*idx64_flag) {
    const long long* e64 = (const long long*)ei;
    sA = (int)e64[eAc]; dA = (int)e64[NEDGE + eAc];
    sB = (int)e64[eBc]; dB = (int)e64[NEDGE + eBc];
  } else {
    sA = ei[eAc]; dA = ei[NEDGE + eAc];
    sB = ei[eBc]; dB = ei[NEDGE + eBc];
  }

  // 16 independent 16B gather loads (4 per kt): U-half of src, V-half of dst
  const u16x8* pAu = (const u16x8*)(UV + (size_t)sA * 256) + q;
  const u16x8* pAv = (const u16x8*)(UV + (size_t)dA * 256 + 128) + q;
  const u16x8* pBu = (const u16x8*)(UV + (size_t)sB * 256) + q;
  const u16x8* pBv = (const u16x8*)(UV + (size_t)dB * 256 + 128) + q;
  u16x8 rAu[4], rAv[4], rBu[4], rBv[4];
#pragma unroll
  for (int kt = 0; kt < 4; ++kt) {
    rAu[kt] = pAu[kt * 4];
    rAv[kt] = pAv[kt * 4];
    rBu[kt] = pBu[kt * 4];
    rBv[kt] = pBv[kt * 4];
  }

  f32x4 acc[2][4];
#pragma unroll
  for (int mt = 0; mt < 2; ++mt)
#pragma unroll
    for (int nt = 0; nt < 4; ++nt) {
      f32x4 zz = {0.f, 0.f, 0.f, 0.f};
      acc[mt][nt] = zz;
    }

#pragma unroll
  for (int kt = 0; kt < 4; ++kt) {
    bf16x8 a0, a1;
#pragma unroll
    for (int j = 0; j < 8; ++j) {
      a0[j] = (__bf16)fmaxf(bf16_f32(rAu[kt][j]) + bf16_f32(rAv[kt][j]), 0.f);
      a1[j] = (__bf16)fmaxf(bf16_f32(rBu[kt][j]) + bf16_f32(rBv[kt][j]), 0.f);
    }
#pragma unroll
    for (int nt = 0; nt < 4; ++nt) {
      bf16x8 bb = *(const bf16x8*)(&lW[(nt * 16 + c) * WPITCH + kt * 32 + q * 8]);
      acc[0][nt] = __builtin_amdgcn_mfma_f32_16x16x32_bf16(a0, bb, acc[0][nt], 0, 0, 0);
      acc[1][nt] = __builtin_amdgcn_mfma_f32_16x16x32_bf16(a1, bb, acc[1][nt], 0, 0, 0);
    }
  }

  // layer-2 bias+relu and layer-3 dot in fp32; reduce over the 16 c-lanes
  float b2v[4], w3v[4];
#pragma unroll
  for (int nt = 0; nt < 4; ++nt) {
    int n = nt * 16 + c;
    b2v[nt] = b2[n];
    w3v[nt] = W3[n];
  }
  float bias3 = b3[0];

#pragma unroll
  for (int mt = 0; mt < 2; ++mt) {
    float p0 = 0.f, p1 = 0.f, p2 = 0.f, p3 = 0.f;
#pragma unroll
    for (int nt = 0; nt < 4; ++nt) {
      p0 += fmaxf(acc[mt][nt][0] + b2v[nt], 0.f) * w3v[nt];
      p1 += fmaxf(acc[mt][nt][1] + b2v[nt], 0.f) * w3v[nt];
      p2 += fmaxf(acc[mt][nt][2] + b2v[nt], 0.f) * w3v[nt];
      p3 += fmaxf(acc[mt][nt][3] + b2v[nt], 0.f) * w3v[nt];
    }
#pragma unroll
    for (int m = 1; m < 16; m <<= 1) {
      p0 += __shfl_xor(p0, m, 64);
      p1 += __shfl_xor(p1, m, 64);
      p2 += __shfl_xor(p2, m, 64);
      p3 += __shfl_xor(p3, m, 64);
    }
    if (c == 0) {
      int eb = ebase + mt * 16 + q * 4;
      if (eb + 0 < NEDGE) out[eb + 0] = p0 + bias3;
      if (eb + 1 < NEDGE) out[eb + 1] = p1 + bias3;
      if (eb + 2 < NEDGE) out[eb + 2] = p2 + bias3;
      if (eb + 3 < NEDGE) out[eb + 3] = p3 + bias3;
    }
  }
}

extern "C" void kernel_launch(void* const* d_in, const int* in_sizes, int n_in,
                              void* d_out, int out_size, void* d_ws, size_t ws_size,
                              hipStream_t stream) {
  const float* z  = (const float*)d_in[0];
  const int*   ei = (const int*)d_in[1];
  const float* W1 = (const float*)d_in[2];
  const float* b1 = (const float*)d_in[3];
  const float* W2 = (const float*)d_in[4];
  const float* b2 = (const float*)d_in[5];
  const float* W3 = (const float*)d_in[6];
  const float* b3 = (const float*)d_in[7];
  float* out = (float*)d_out;

  unsigned short* UV  = (unsigned short*)d_ws;       // 50000*256 bf16 = 25.6 MB
  unsigned short* W2T = UV + (size_t)NNODE * 256;    // 64*128 bf16
  int* idx64_flag     = (int*)(W2T + 64 * 128);

  uv_kernel<<<dim3((NNODE + 63) / 64), dim3(256), 0, stream>>>(
      z, W1, b1, W2, ei, UV, W2T, idx64_flag);
  edge_kernel<<<dim3((NEDGE + 127) / 128), dim3(256), 0, stream>>>(
      ei, UV, W2T, b2, W3, b3, idx64_flag, out);
}

// Round 10
// 143.354 us; speedup vs baseline: 1.7440x; 1.0646x over previous
//
#include <hip/hip_runtime.h>

#define NEDGE 625000
#define NNODE 50000
#define NUNIT ((NNODE + 15) / 16)  // 3125 16-row units
#define WPITCH 136  // lW pitch in shorts: 272 B rows -> 2-way bank aliasing on b128 (free)
#define EPITCH 68   // uv epilogue pitch in shorts
#define WCPITCH 136 // in-LDS Wcat pitch in shorts: b128 reads 2-way (free), b128 writes even-8 (min)

typedef __bf16 bf16x8 __attribute__((ext_vector_type(8)));
typedef unsigned short u16x8 __attribute__((ext_vector_type(8)));
typedef float f32x4 __attribute__((ext_vector_type(4)));

// Native casts: __bf16 cast is RNE in HW; compiler pairs them (v_cvt_pk_bf16_f32).
__device__ __forceinline__ unsigned short f32_bf16(float f) {
  __bf16 h = (__bf16)f;
  return __builtin_bit_cast(unsigned short, h);
}
__device__ __forceinline__ float bf16_f32(unsigned short h) {
  return (float)__builtin_bit_cast(__bf16, h);
}

// ---------------------------------------------------------------------------
// uv: UV[n][0:128] = z[n]@W1_top + b1, UV[n][128:256] = z[n]@W1_bot  (bf16)
// v6: transpose vectorized + 512 persistent blocks (exactly 2/CU).
//   - Old transpose: 128 iter/thread of {load, cvt, ds_write_b16} where the
//     b16 writes (lane stride 68 dwords -> banks 4 apart) were 8-WAY
//     CONFLICTED (~2.9x, m136). New: thread t owns Wcat row j'=t; per octet
//     it does 8 coalesced W1 loads + ONE ds_write_b128. At pitch 136, b128
//     writes land exactly 8 dword-accesses/bank (perfectly even = minimum).
//     Write instrs 128 -> 16 per thread, conflicts gone.
//   - 512 blocks = one full 2-blocks/CU generation; grid-stride unit loop
//     removes the 782-block tail imbalance; transposes/CU 3.05 -> 2.
// Side jobs (blocks 0-1): W2T bf16 + idx64_flag for edge_kernel.
// ---------------------------------------------------------------------------
__global__ __launch_bounds__(256, 2) void uv_kernel(
    const float* __restrict__ z, const float* __restrict__ W1,
    const float* __restrict__ b1, const float* __restrict__ W2,
    const int* __restrict__ ei,
    unsigned short* __restrict__ UV, unsigned short* __restrict__ W2T,
    int* __restrict__ idx64_flag)
{
  __shared__ unsigned short lWc[256 * WCPITCH];  // Wcat[j'][k], 69632 B
  __shared__ unsigned short st[4 * 16 * EPITCH]; // per-wave epilogue, 8704 B
  const int t = threadIdx.x, wave = t >> 6, lane = t & 63, c = lane & 15, q = lane >> 4;
  const int bid = blockIdx.x;

  // side jobs for edge_kernel (cross-kernel-boundary handoff)
  if (bid < 2) {
    for (int e = bid * 4096 + t; e < (bid + 1) * 4096; e += 256) {
      int n = e >> 7, k = e & 127;
      W2T[n * 128 + k] = f32_bf16(W2[k * 64 + n]);
    }
  }
  if (bid == 0 && t == 0) {
    int allz = 1;
    for (int j = 1; j < 64; j += 2) allz &= (ei[j] == 0);
    *idx64_flag = allz;
  }

  // vectorized in-LDS transpose: thread t owns row j'=t of Wcat.
  // Wcat[j'][k] = W1[k][j']         (j' < 128)
  //            = W1[128+k][j'-128]  (j' >= 128)
  {
    const float* src = (t < 128) ? (W1 + t) : (W1 + 128 * 128 + (t - 128));
#pragma unroll 4
    for (int oct = 0; oct < 16; ++oct) {
      float v[8];
#pragma unroll
      for (int ii = 0; ii < 8; ++ii) v[ii] = src[(size_t)(oct * 8 + ii) * 128];
      bf16x8 o;
#pragma unroll
      for (int ii = 0; ii < 8; ++ii) o[ii] = (__bf16)v[ii];
      *(bf16x8*)(&lWc[t * WCPITCH + oct * 8]) = o;
    }
  }
  __syncthreads();

  unsigned short* my = &st[wave * 16 * EPITCH];

  for (int gw = bid * 4 + wave; gw < NUNIT; gw += 512 * 4) {
    const int mbase = gw * 16;
    const int rA = mbase + c;
    const int rAc = (rA < NNODE) ? rA : 0;

    // A-fragments: 8 fp32 each at z[row][kt*32+q*8], convert to bf16 in regs
    bf16x8 a0[4];
    {
      const float* zA = z + (size_t)rAc * 128 + q * 8;
      float4 fA[4][2];
#pragma unroll
      for (int kt = 0; kt < 4; ++kt) {
        fA[kt][0] = ((const float4*)(zA + kt * 32))[0];
        fA[kt][1] = ((const float4*)(zA + kt * 32))[1];
      }
#pragma unroll
      for (int kt = 0; kt < 4; ++kt) {
        const float* pa = (const float*)&fA[kt][0];
        bf16x8 oa;
#pragma unroll
        for (int j = 0; j < 8; ++j) oa[j] = (__bf16)pa[j];
        a0[kt] = oa;
      }
    }

    for (int nc = 0; nc < 4; ++nc) {
      f32x4 acc[4];
#pragma unroll
      for (int nt = 0; nt < 4; ++nt) {
        f32x4 zz = {0.f, 0.f, 0.f, 0.f};
        acc[nt] = zz;
      }
#pragma unroll
      for (int kt = 0; kt < 4; ++kt)
#pragma unroll
        for (int nt = 0; nt < 4; ++nt) {
          bf16x8 bb = *(const bf16x8*)(&lWc[(nc * 64 + nt * 16 + c) * WCPITCH + kt * 32 + q * 8]);
          acc[nt] = __builtin_amdgcn_mfma_f32_16x16x32_bf16(a0[kt], bb, acc[nt], 0, 0, 0);
        }

      float badd[4];
#pragma unroll
      for (int nt = 0; nt < 4; ++nt) {
        int col = nc * 64 + nt * 16 + c;
        badd[nt] = (col < 128) ? b1[col] : 0.f;
      }

      // stage C-chunk (16 rows x 64 cols = 1024 shorts) in wave-private LDS
#pragma unroll
      for (int nt = 0; nt < 4; ++nt)
#pragma unroll
        for (int reg = 0; reg < 4; ++reg)
          my[(q * 4 + reg) * EPITCH + nt * 16 + c] = f32_bf16(acc[nt][reg] + badd[nt]);
      __asm__ volatile("s_waitcnt lgkmcnt(0)" ::: "memory");  // wave-private: ds_write->ds_read

      // vectorized store: each lane takes 16 shorts (32 B)
      {
        int lrow = lane >> 2, qt = lane & 3;
        int grow = mbase + lrow;
        u16x8 d0 = *(u16x8*)&my[lrow * EPITCH + qt * 16 + 0];
        u16x8 d1 = *(u16x8*)&my[lrow * EPITCH + qt * 16 + 8];
        if (grow < NNODE) {
          u16x8* dst = (u16x8*)(UV + (size_t)grow * 256 + nc * 64 + qt * 16);
          dst[0] = d0;
          dst[1] = d1;
        }
      }
      __asm__ volatile("s_waitcnt lgkmcnt(0)" ::: "memory");  // reads drain before next chunk overwrites
    }
  }
}

// ---------------------------------------------------------------------------
// edge: gather MFMA A-frags DIRECTLY from UV (no h1 LDS, no gather barrier):
// lane (c,q) reads 16B granules of rows src/dst; add+relu in regs -> frags.
// h2 = relu(h1@W2+b2) via MFMA (W2T staged once in LDS); score fp32 epilogue.
// PROVEN config (51.4-53.6 us, 7x reproduced): native casts +
// launch_bounds(256,4), NO sched fence. Bidirectional sweep complete:
// deeper queues (r2) worse, more waves (r7: spills) worse, less HBM traffic
// via src-bucketing (r8: FETCH 135->108 MB) ALSO worse — the kernel sits at
// the random-64B-segment service equilibrium (~320 MB mandatory gathers at
// ~6.1 TB/s blended L1/L2/L3 ~= 52 us). DO NOT TOUCH.
// ---------------------------------------------------------------------------
__global__ __launch_bounds__(256, 4) void edge_kernel(
    const int* __restrict__ ei,
    const unsigned short* __restrict__ UV,
    const unsigned short* __restrict__ W2T,
    const float* __restrict__ b2, const float* __restrict__ W3,
    const float* __restrict__ b3, const int* __restrict__ idx64_flag,
    float* __restrict__ out)
{
  __shared__ unsigned short lW[64 * WPITCH];
  const int t = threadIdx.x, wave = t >> 6, lane = t & 63, c = lane & 15, q = lane >> 4;

  {  // stage W2T once (16 KB shared by all waves)
    int n = t >> 2, qd = t & 3;
    const u16x8* src = (const u16x8*)(W2T + n * 128 + qd * 32);
    u16x8* dst = (u16x8*)(&lW[n * WPITCH + qd * 32]);
#pragma unroll
    for (int i = 0; i < 4; ++i) dst[i] = src[i];
  }
  __syncthreads();  // the only barrier in this kernel

  const int ebase = blockIdx.x * 128 + wave * 32;
  const int eA = ebase + c, eB = ebase + 16 + c;
  const int eAc = (eA < NEDGE) ? eA : 0;
  const int eBc = (eB < NEDGE) ? eB : 0;
  int sA, dA, sB, dB;
  if (*idx64_flag) {
    const long long* e64 = (const long long*)ei;
    sA = (int)e64[eAc]; dA = (int)e64[NEDGE + eAc];
    sB = (int)e64[eBc]; dB = (int)e64[NEDGE + eBc];
  } else {
    sA = ei[eAc]; dA = ei[NEDGE + eAc];
    sB = ei[eBc]; dB = ei[NEDGE + eBc];
  }

  // 16 independent 16B gather loads (4 per kt): U-half of src, V-half of dst
  const u16x8* pAu = (const u16x8*)(UV + (size_t)sA * 256) + q;
  const u16x8* pAv = (const u16x8*)(UV + (size_t)dA * 256 + 128) + q;
  const u16x8* pBu = (const u16x8*)(UV + (size_t)sB * 256) + q;
  const u16x8* pBv = (const u16x8*)(UV + (size_t)dB * 256 + 128) + q;
  u16x8 rAu[4], rAv[4], rBu[4], rBv[4];
#pragma unroll
  for (int kt = 0; kt < 4; ++kt) {
    rAu[kt] = pAu[kt * 4];
    rAv[kt] = pAv[kt * 4];
    rBu[kt] = pBu[kt * 4];
    rBv[kt] = pBv[kt * 4];
  }

  f32x4 acc[2][4];
#pragma unroll
  for (int mt = 0; mt < 2; ++mt)
#pragma unroll
    for (int nt = 0; nt < 4; ++nt) {
      f32x4 zz = {0.f, 0.f, 0.f, 0.f};
      acc[mt][nt] = zz;
    }

#pragma unroll
  for (int kt = 0; kt < 4; ++kt) {
    bf16x8 a0, a1;
#pragma unroll
    for (int j = 0; j < 8; ++j) {
      a0[j] = (__bf16)fmaxf(bf16_f32(rAu[kt][j]) + bf16_f32(rAv[kt][j]), 0.f);
      a1[j] = (__bf16)fmaxf(bf16_f32(rBu[kt][j]) + bf16_f32(rBv[kt][j]), 0.f);
    }
#pragma unroll
    for (int nt = 0; nt < 4; ++nt) {
      bf16x8 bb = *(const bf16x8*)(&lW[(nt * 16 + c) * WPITCH + kt * 32 + q * 8]);
      acc[0][nt] = __builtin_amdgcn_mfma_f32_16x16x32_bf16(a0, bb, acc[0][nt], 0, 0, 0);
      acc[1][nt] = __builtin_amdgcn_mfma_f32_16x16x32_bf16(a1, bb, acc[1][nt], 0, 0, 0);
    }
  }

  // layer-2 bias+relu and layer-3 dot in fp32; reduce over the 16 c-lanes
  float b2v[4], w3v[4];
#pragma unroll
  for (int nt = 0; nt < 4; ++nt) {
    int n = nt * 16 + c;
    b2v[nt] = b2[n];
    w3v[nt] = W3[n];
  }
  float bias3 = b3[0];

#pragma unroll
  for (int mt = 0; mt < 2; ++mt) {
    float p0 = 0.f, p1 = 0.f, p2 = 0.f, p3 = 0.f;
#pragma unroll
    for (int nt = 0; nt < 4; ++nt) {
      p0 += fmaxf(acc[mt][nt][0] + b2v[nt], 0.f) * w3v[nt];
      p1 += fmaxf(acc[mt][nt][1] + b2v[nt], 0.f) * w3v[nt];
      p2 += fmaxf(acc[mt][nt][2] + b2v[nt], 0.f) * w3v[nt];
      p3 += fmaxf(acc[mt][nt][3] + b2v[nt], 0.f) * w3v[nt];
    }
#pragma unroll
    for (int m = 1; m < 16; m <<= 1) {
      p0 += __shfl_xor(p0, m, 64);
      p1 += __shfl_xor(p1, m, 64);
      p2 += __shfl_xor(p2, m, 64);
      p3 += __shfl_xor(p3, m, 64);
    }
    if (c == 0) {
      int eb = ebase + mt * 16 + q * 4;
      if (eb + 0 < NEDGE) out[eb + 0] = p0 + bias3;
      if (eb + 1 < NEDGE) out[eb + 1] = p1 + bias3;
      if (eb + 2 < NEDGE) out[eb + 2] = p2 + bias3;
      if (eb + 3 < NEDGE) out[eb + 3] = p3 + bias3;
    }
  }
}

extern "C" void kernel_launch(void* const* d_in, const int* in_sizes, int n_in,
                              void* d_out, int out_size, void* d_ws, size_t ws_size,
                              hipStream_t stream) {
  const float* z  = (const float*)d_in[0];
  const int*   ei = (const int*)d_in[1];
  const float* W1 = (const float*)d_in[2];
  const float* b1 = (const float*)d_in[3];
  const float* W2 = (const float*)d_in[4];
  const float* b2 = (const float*)d_in[5];
  const float* W3 = (const float*)d_in[6];
  const float* b3 = (const float*)d_in[7];
  float* out = (float*)d_out;

  unsigned short* UV  = (unsigned short*)d_ws;       // 50000*256 bf16 = 25.6 MB
  unsigned short* W2T = UV + (size_t)NNODE * 256;    // 64*128 bf16
  int* idx64_flag     = (int*)(W2T + 64 * 128);

  uv_kernel<<<dim3(512), dim3(256), 0, stream>>>(
      z, W1, b1, W2, ei, UV, W2T, idx64_flag);
  edge_kernel<<<dim3((NEDGE + 127) / 128), dim3(256), 0, stream>>>(
      ei, UV, W2T, b2, W3, b3, idx64_flag, out);
}